// Round 2
// baseline (654.372 us; speedup 1.0000x reference)
//
#include <hip/hip_runtime.h>
#include <hip/hip_bf16.h>

#define N_PTS 300000
#define GXD 480
#define GYD 360
#define NBATCH 4
#define NVOX (NBATCH * GXD * GYD)
#define OUTC 64
#define BN_EPS 1e-5f

typedef __attribute__((ext_vector_type(8))) __bf16 bf16x8;
typedef __attribute__((ext_vector_type(4))) float f32x4;

__device__ __forceinline__ unsigned encf(float f) {
    unsigned u = __float_as_uint(f);
    return (u & 0x80000000u) ? ~u : (u | 0x80000000u);
}
__device__ __forceinline__ float decf(unsigned e) {
    return __uint_as_float((e & 0x80000000u) ? (e & 0x7fffffffu) : ~e);
}

__device__ __forceinline__ f32x4 mfma16(bf16x8 a, bf16x8 b, f32x4 c) {
    return __builtin_amdgcn_mfma_f32_16x16x32_bf16(a, b, c, 0, 0, 0);
}

// ---------------------------------------------------------------------------
// Fold BN(eval) into linear weights. Store weights TRANSPOSED [Nout][Kpad] bf16
// so MFMA B-fragments are contiguous 16B loads. Biases fp32.
// ---------------------------------------------------------------------------
__global__ __launch_bounds__(256) void fold_kernel(
    const float* __restrict__ bn0g, const float* __restrict__ bn0b,
    const float* __restrict__ bn0m, const float* __restrict__ bn0v,
    const float* __restrict__ bn1g, const float* __restrict__ bn1b,
    const float* __restrict__ bn1m, const float* __restrict__ bn1v,
    const float* __restrict__ bn2g, const float* __restrict__ bn2b,
    const float* __restrict__ bn2m, const float* __restrict__ bn2v,
    const float* __restrict__ bn3g, const float* __restrict__ bn3b,
    const float* __restrict__ bn3m, const float* __restrict__ bn3v,
    const float* __restrict__ w1, const float* __restrict__ bb1,
    const float* __restrict__ w2, const float* __restrict__ bb2,
    const float* __restrict__ w3, const float* __restrict__ bb3,
    const float* __restrict__ w4, const float* __restrict__ bb4,
    __bf16* __restrict__ W1fT, __bf16* __restrict__ W2fT,
    __bf16* __restrict__ W3fT, __bf16* __restrict__ W4T,
    float* __restrict__ Bf)
{
    const int tid = blockIdx.x * blockDim.x + threadIdx.x;
    const int nth = gridDim.x * blockDim.x;

    // W1fT [64][32]: (k<9) s0[k]*w1[k][n]*s1[n] else 0
    for (int i = tid; i < 64 * 32; i += nth) {
        int n = i >> 5, k = i & 31;
        float v = 0.f;
        if (k < 9) {
            float s0 = bn0g[k] * rsqrtf(bn0v[k] + BN_EPS);
            float s1 = bn1g[n] * rsqrtf(bn1v[n] + BN_EPS);
            v = s0 * w1[k * 64 + n] * s1;
        }
        W1fT[i] = (__bf16)v;
    }
    // B1f [64]
    for (int n = tid; n < 64; n += nth) {
        float s1 = bn1g[n] * rsqrtf(bn1v[n] + BN_EPS);
        float t1 = bn1b[n] - bn1m[n] * s1;
        float dot = 0.f;
        for (int k = 0; k < 9; k++) {
            float s0 = bn0g[k] * rsqrtf(bn0v[k] + BN_EPS);
            float t0 = bn0b[k] - bn0m[k] * s0;
            dot += t0 * w1[k * 64 + n];
        }
        Bf[n] = (dot + bb1[n]) * s1 + t1;
    }
    // W2fT [128][64]
    for (int i = tid; i < 128 * 64; i += nth) {
        int n = i >> 6, k = i & 63;
        float s2 = bn2g[n] * rsqrtf(bn2v[n] + BN_EPS);
        W2fT[i] = (__bf16)(w2[k * 128 + n] * s2);
    }
    for (int n = tid; n < 128; n += nth) {
        float s2 = bn2g[n] * rsqrtf(bn2v[n] + BN_EPS);
        Bf[64 + n] = bb2[n] * s2 + (bn2b[n] - bn2m[n] * s2);
    }
    // W3fT [256][128]
    for (int i = tid; i < 256 * 128; i += nth) {
        int n = i >> 7, k = i & 127;
        float s3 = bn3g[n] * rsqrtf(bn3v[n] + BN_EPS);
        W3fT[i] = (__bf16)(w3[k * 256 + n] * s3);
    }
    for (int n = tid; n < 256; n += nth) {
        float s3 = bn3g[n] * rsqrtf(bn3v[n] + BN_EPS);
        Bf[192 + n] = bb3[n] * s3 + (bn3b[n] - bn3m[n] * s3);
    }
    // W4T [64][256]
    for (int i = tid; i < 64 * 256; i += nth) {
        int n = i >> 8, k = i & 255;
        W4T[i] = (__bf16)w4[k * 64 + n];
    }
    for (int n = tid; n < 64; n += nth) Bf[448 + n] = bb4[n];
}

// ---------------------------------------------------------------------------
// Grid init: encoded-empty marker = 0u (below every encoded real value).
// ---------------------------------------------------------------------------
__global__ __launch_bounds__(256) void init_grid(uint4* __restrict__ g) {
    g[blockIdx.x * 256 + threadIdx.x] = make_uint4(0u, 0u, 0u, 0u);
}

// ---------------------------------------------------------------------------
// Fused MLP (MFMA, bf16) + atomicMax scatter. 64 points/block, 16/wave.
// All LDS deps are intra-wave -> no __syncthreads.
// ---------------------------------------------------------------------------
__global__ __launch_bounds__(256) void mlp_scatter(
    const float* __restrict__ x, const int* __restrict__ bidx,
    const int* __restrict__ gx, const int* __restrict__ gy,
    const __bf16* __restrict__ W1, const __bf16* __restrict__ W2,
    const __bf16* __restrict__ W3, const __bf16* __restrict__ W4,
    const float* __restrict__ Bf, unsigned* __restrict__ grid)
{
    __shared__ __bf16 bufA[4][16][264];  // max width 256 (+8 pad)
    __shared__ __bf16 bufB[4][16][136];  // max width 128 (+8 pad)
    __shared__ int voxl[64];

    const int tid = threadIdx.x;
    const int wid = tid >> 6, lane = tid & 63;
    const int col = lane & 15, kg = lane >> 4;
    const int base = blockIdx.x * 64;

    if (lane < 16) {
        int p = base + wid * 16 + lane;
        int v = 0;
        if (p < N_PTS) v = (bidx[p] * GXD + gx[p]) * GYD + gy[p];
        voxl[wid * 16 + lane] = v;
    }

    // ---- L1: 9(->32 pad) -> 64, A straight from global
    const int p0 = base + wid * 16 + col;
    bf16x8 a1;
#pragma unroll
    for (int j = 0; j < 8; j++) a1[j] = (__bf16)0.f;
    if (p0 < N_PTS) {
        const float* xp = x + p0 * 9;
#pragma unroll
        for (int j = 0; j < 8; j++) {
            int k = kg * 8 + j;
            if (k < 9) a1[j] = (__bf16)xp[k];
        }
    }
    f32x4 acc1[4];
#pragma unroll
    for (int nt = 0; nt < 4; nt++) {
        float bv = Bf[nt * 16 + col];
        acc1[nt] = (f32x4){bv, bv, bv, bv};
        bf16x8 b = *(const bf16x8*)(W1 + (nt * 16 + col) * 32 + kg * 8);
        acc1[nt] = mfma16(a1, b, acc1[nt]);
    }
#pragma unroll
    for (int nt = 0; nt < 4; nt++)
#pragma unroll
        for (int r = 0; r < 4; r++) {
            float v = acc1[nt][r];
            bufA[wid][kg * 4 + r][nt * 16 + col] = (__bf16)(v > 0.f ? v : 0.f);
        }

    // ---- L2: 64 -> 128
    bf16x8 a2[2];
#pragma unroll
    for (int kt = 0; kt < 2; kt++)
        a2[kt] = *(const bf16x8*)&bufA[wid][col][kt * 32 + kg * 8];
    f32x4 acc2[8];
#pragma unroll
    for (int nt = 0; nt < 8; nt++) {
        float bv = Bf[64 + nt * 16 + col];
        acc2[nt] = (f32x4){bv, bv, bv, bv};
#pragma unroll
        for (int kt = 0; kt < 2; kt++) {
            bf16x8 b = *(const bf16x8*)(W2 + (nt * 16 + col) * 64 + kt * 32 + kg * 8);
            acc2[nt] = mfma16(a2[kt], b, acc2[nt]);
        }
    }
#pragma unroll
    for (int nt = 0; nt < 8; nt++)
#pragma unroll
        for (int r = 0; r < 4; r++) {
            float v = acc2[nt][r];
            bufB[wid][kg * 4 + r][nt * 16 + col] = (__bf16)(v > 0.f ? v : 0.f);
        }

    // ---- L3: 128 -> 256
    bf16x8 a3[4];
#pragma unroll
    for (int kt = 0; kt < 4; kt++)
        a3[kt] = *(const bf16x8*)&bufB[wid][col][kt * 32 + kg * 8];
    f32x4 acc3[16];
#pragma unroll
    for (int nt = 0; nt < 16; nt++) {
        float bv = Bf[192 + nt * 16 + col];
        acc3[nt] = (f32x4){bv, bv, bv, bv};
#pragma unroll
        for (int kt = 0; kt < 4; kt++) {
            bf16x8 b = *(const bf16x8*)(W3 + (nt * 16 + col) * 128 + kt * 32 + kg * 8);
            acc3[nt] = mfma16(a3[kt], b, acc3[nt]);
        }
    }
#pragma unroll
    for (int nt = 0; nt < 16; nt++)
#pragma unroll
        for (int r = 0; r < 4; r++) {
            float v = acc3[nt][r];
            bufA[wid][kg * 4 + r][nt * 16 + col] = (__bf16)(v > 0.f ? v : 0.f);
        }

    // ---- L4: 256 -> 64 (no relu)
    bf16x8 a4[8];
#pragma unroll
    for (int kt = 0; kt < 8; kt++)
        a4[kt] = *(const bf16x8*)&bufA[wid][col][kt * 32 + kg * 8];
    f32x4 acc4[4];
#pragma unroll
    for (int nt = 0; nt < 4; nt++) {
        float bv = Bf[448 + nt * 16 + col];
        acc4[nt] = (f32x4){bv, bv, bv, bv};
#pragma unroll
        for (int kt = 0; kt < 8; kt++) {
            bf16x8 b = *(const bf16x8*)(W4 + (nt * 16 + col) * 256 + kt * 32 + kg * 8);
            acc4[nt] = mfma16(a4[kt], b, acc4[nt]);
        }
    }

    // ---- scatter: atomicMax on order-preserving encoding
#pragma unroll
    for (int nt = 0; nt < 4; nt++) {
        int ch = nt * 16 + col;
#pragma unroll
        for (int r = 0; r < 4; r++) {
            int m = kg * 4 + r;
            int p = base + wid * 16 + m;
            if (p < N_PTS) {
                unsigned e = encf(acc4[nt][r]);
                atomicMax(grid + (long)voxl[wid * 16 + m] * 64 + ch, e);
            }
        }
    }
}

// ---------------------------------------------------------------------------
// 3x3 stride-1 maxpool + transpose [b][x][y][c] -> [b][c][x][y], FP32 out
// (reference output dtype is float32). Block: 4 x-rows x 32 y x all 64 c.
// ---------------------------------------------------------------------------
__global__ __launch_bounds__(256) void pool_kernel(
    const unsigned* __restrict__ grid, float* __restrict__ out)
{
    __shared__ unsigned tile[6][34][65];
    const int tid = threadIdx.x;
    const int x0 = blockIdx.x * 4;
    const int y0 = blockIdx.y * 32;
    const int b = blockIdx.z;

    for (int it = 0; it < 13; it++) {
        int idx = it * 256 + tid;
        if (idx < 6 * 34 * 16) {
            int c4 = idx & 15;
            int yy = (idx >> 4) % 34;
            int xx = (idx >> 4) / 34;
            int gxx = x0 - 1 + xx;
            int gyy = y0 - 1 + yy;
            uint4 v = make_uint4(0u, 0u, 0u, 0u);  // OOB -> -inf marker
            if (gxx >= 0 && gxx < GXD && gyy >= 0 && gyy < GYD) {
                v = *(const uint4*)(grid + ((long)(b * GXD + gxx) * GYD + gyy) * 64 + c4 * 4);
                // in-bounds empty voxel -> enc(0.0f)
                v.x = v.x ? v.x : 0x80000000u;
                v.y = v.y ? v.y : 0x80000000u;
                v.z = v.z ? v.z : 0x80000000u;
                v.w = v.w ? v.w : 0x80000000u;
            }
            unsigned* t = &tile[xx][yy][c4 * 4];
            t[0] = v.x; t[1] = v.y; t[2] = v.z; t[3] = v.w;
        }
    }
    __syncthreads();

    const int y = tid & 31;
    const int cg = tid >> 5;
    const bool yv = (y0 + y) < GYD;
#pragma unroll
    for (int cs = 0; cs < 8; cs++) {
        int c = cg * 8 + cs;
        unsigned rowm[6];
#pragma unroll
        for (int xx = 0; xx < 6; xx++) {
            unsigned e0 = tile[xx][y][c];
            unsigned e1 = tile[xx][y + 1][c];
            unsigned e2 = tile[xx][y + 2][c];
            unsigned m = e0 > e1 ? e0 : e1;
            rowm[xx] = m > e2 ? m : e2;
        }
        if (yv) {
#pragma unroll
            for (int xo = 0; xo < 4; xo++) {
                unsigned m = rowm[xo] > rowm[xo + 1] ? rowm[xo] : rowm[xo + 1];
                m = m > rowm[xo + 2] ? m : rowm[xo + 2];
                out[((long)(b * OUTC + c) * GXD + (x0 + xo)) * GYD + (y0 + y)] =
                    decf(m);
            }
        }
    }
}

extern "C" void kernel_launch(void* const* d_in, const int* in_sizes, int n_in,
                              void* d_out, int out_size, void* d_ws, size_t ws_size,
                              hipStream_t stream)
{
    const float* pt   = (const float*)d_in[0];
    const int* bidx   = (const int*)d_in[1];
    const int* gxp    = (const int*)d_in[2];
    const int* gyp    = (const int*)d_in[3];
    const float* bn0g = (const float*)d_in[4],  *bn0b = (const float*)d_in[5];
    const float* bn0m = (const float*)d_in[6],  *bn0v = (const float*)d_in[7];
    const float* bn1g = (const float*)d_in[8],  *bn1b = (const float*)d_in[9];
    const float* bn1m = (const float*)d_in[10], *bn1v = (const float*)d_in[11];
    const float* bn2g = (const float*)d_in[12], *bn2b = (const float*)d_in[13];
    const float* bn2m = (const float*)d_in[14], *bn2v = (const float*)d_in[15];
    const float* bn3g = (const float*)d_in[16], *bn3b = (const float*)d_in[17];
    const float* bn3m = (const float*)d_in[18], *bn3v = (const float*)d_in[19];
    const float* w1 = (const float*)d_in[20], *bb1 = (const float*)d_in[21];
    const float* w2 = (const float*)d_in[22], *bb2 = (const float*)d_in[23];
    const float* w3 = (const float*)d_in[24], *bb3 = (const float*)d_in[25];
    const float* w4 = (const float*)d_in[26], *bb4 = (const float*)d_in[27];

    char* ws = (char*)d_ws;
    __bf16* W1fT = (__bf16*)ws;              // 64*32
    __bf16* W2fT = W1fT + 64 * 32;           // 128*64
    __bf16* W3fT = W2fT + 128 * 64;          // 256*128
    __bf16* W4T  = W3fT + 256 * 128;         // 64*256
    float* Bf = (float*)(ws + 2 * (64 * 32 + 128 * 64 + 256 * 128 + 64 * 256));
    unsigned* grid = (unsigned*)(ws + 131072);  // 128KB-aligned; 176.9 MB

    hipLaunchKernelGGL(fold_kernel, dim3(64), dim3(256), 0, stream,
                       bn0g, bn0b, bn0m, bn0v, bn1g, bn1b, bn1m, bn1v,
                       bn2g, bn2b, bn2m, bn2v, bn3g, bn3b, bn3m, bn3v,
                       w1, bb1, w2, bb2, w3, bb3, w4, bb4,
                       W1fT, W2fT, W3fT, W4T, Bf);

    // NVOX*OUTC = 44,236,800 u32 = 11,059,200 uint4 = 43200 * 256
    hipLaunchKernelGGL(init_grid, dim3(43200), dim3(256), 0, stream, (uint4*)grid);

    hipLaunchKernelGGL(mlp_scatter, dim3((N_PTS + 63) / 64), dim3(256), 0, stream,
                       pt, bidx, gxp, gyp, W1fT, W2fT, W3fT, W4T, Bf, grid);

    hipLaunchKernelGGL(pool_kernel, dim3(GXD / 4, (GYD + 31) / 32, NBATCH),
                       dim3(256), 0, stream, grid, (float*)d_out);
}